// Round 6
// baseline (3382.880 us; speedup 1.0000x reference)
//
#include <hip/hip_runtime.h>
#include <math.h>

typedef __bf16 bf16x8 __attribute__((ext_vector_type(8)));
typedef float f32x4 __attribute__((ext_vector_type(4)));
typedef unsigned short u16;
typedef unsigned short u16x4 __attribute__((ext_vector_type(4)));
typedef unsigned short u16x8 __attribute__((ext_vector_type(8)));
typedef unsigned int u32;

#define AS1 __attribute__((address_space(1)))
#define AS3 __attribute__((address_space(3)))

static __device__ __forceinline__ float bf2f(u16 u) {
  union { u32 i; float f; } v; v.i = ((u32)u) << 16; return v.f;
}
static __device__ __forceinline__ u16 f2bf(float f) {
  union { float f; u32 i; } v; v.f = f;
  u32 r = v.i + 0x7FFFu + ((v.i >> 16) & 1u);
  return (u16)(r >> 16);
}

// ---- GEMM: C[M,N] = A[M,K] @ B[N,K]^T; A/B fp32 or bf16; C bf16 or fp32 ----
// 128x128 tile, BK=32, 4 waves (2x2), 16x mfma_16x16x32_bf16 per wave/K-step.
template <bool AF32, bool BF32, bool CF32>
__global__ __launch_bounds__(256, 2)
void gemm_bt(const void* __restrict__ Ap, const void* __restrict__ Bp,
             void* __restrict__ Cp, int M, int N, int K) {
  __shared__ __align__(16) u16 As[128 * 32];
  __shared__ __align__(16) u16 Bs[128 * 32];
  const int tid = threadIdx.x;
  const int lane = tid & 63;
  const int wid = tid >> 6;
  const int wr = wid >> 1, wc = wid & 1;
  const int l15 = lane & 15, l4 = lane >> 4;
  const int m0 = blockIdx.y * 128, n0 = blockIdx.x * 128;
  const float* Af = (const float*)Ap;
  const u16*   Ab = (const u16*)Ap;
  const float* Bf = (const float*)Bp;
  const u16*   Bb = (const u16*)Bp;

  const f32x4 fzero = {0.f, 0.f, 0.f, 0.f};
  f32x4 acc[4][4];
#pragma unroll
  for (int i = 0; i < 4; ++i)
#pragma unroll
    for (int j = 0; j < 4; ++j) acc[i][j] = fzero;

  for (int kt = 0; kt < K; kt += 32) {
    float4 ar[4], br[4];
    if constexpr (AF32) {
#pragma unroll
      for (int i = 0; i < 4; ++i) {
        const int q = i * 256 + tid;  // 0..1023: row=q>>3, col4=q&7
        ar[i] = *(const float4*)(Af + (size_t)(m0 + (q >> 3)) * K + kt + (q & 7) * 4);
      }
    } else {
#pragma unroll
      for (int i = 0; i < 2; ++i) {
        const int c = wid * 64 + i * 256 + lane;  // 0..511: row=c>>2, col8=c&3
        const u16* ga = Ab + (size_t)(m0 + (c >> 2)) * K + kt + (c & 3) * 8;
        __builtin_amdgcn_global_load_lds((AS1 void*)ga,
            (AS3 void*)(As + (size_t)(wid * 64 + i * 256) * 8), 16, 0, 0);
      }
    }
    if constexpr (BF32) {
#pragma unroll
      for (int i = 0; i < 4; ++i) {
        const int q = i * 256 + tid;
        br[i] = *(const float4*)(Bf + (size_t)(n0 + (q >> 3)) * K + kt + (q & 7) * 4);
      }
    } else {
#pragma unroll
      for (int i = 0; i < 2; ++i) {
        const int c = wid * 64 + i * 256 + lane;
        const u16* gb = Bb + (size_t)(n0 + (c >> 2)) * K + kt + (c & 3) * 8;
        __builtin_amdgcn_global_load_lds((AS1 void*)gb,
            (AS3 void*)(Bs + (size_t)(wid * 64 + i * 256) * 8), 16, 0, 0);
      }
    }
    __syncthreads();
    if constexpr (AF32) {
#pragma unroll
      for (int i = 0; i < 4; ++i) {
        const int q = i * 256 + tid;
        u16x4 p = {f2bf(ar[i].x), f2bf(ar[i].y), f2bf(ar[i].z), f2bf(ar[i].w)};
        *(u16x4*)&As[(q >> 3) * 32 + (q & 7) * 4] = p;
      }
    }
    if constexpr (BF32) {
#pragma unroll
      for (int i = 0; i < 4; ++i) {
        const int q = i * 256 + tid;
        u16x4 p = {f2bf(br[i].x), f2bf(br[i].y), f2bf(br[i].z), f2bf(br[i].w)};
        *(u16x4*)&Bs[(q >> 3) * 32 + (q & 7) * 4] = p;
      }
    }
    if constexpr (AF32 || BF32) __syncthreads();
    bf16x8 af[4], bfr[4];
#pragma unroll
    for (int m = 0; m < 4; ++m)
      af[m] = *(const bf16x8*)&As[(wr * 64 + m * 16 + l15) * 32 + l4 * 8];
#pragma unroll
    for (int n = 0; n < 4; ++n)
      bfr[n] = *(const bf16x8*)&Bs[(wc * 64 + n * 16 + l15) * 32 + l4 * 8];
#pragma unroll
    for (int m = 0; m < 4; ++m)
#pragma unroll
      for (int n = 0; n < 4; ++n)
        acc[m][n] = __builtin_amdgcn_mfma_f32_16x16x32_bf16(af[m], bfr[n], acc[m][n], 0, 0, 0);
    if constexpr (!AF32 || !BF32) __syncthreads();
  }

  // C/D: row=(lane>>4)*4+r, col=lane&15
#pragma unroll
  for (int m = 0; m < 4; ++m)
#pragma unroll
    for (int r = 0; r < 4; ++r) {
      const int gm = m0 + wr * 64 + m * 16 + l4 * 4 + r;
      if constexpr (CF32) {
        float* crow = (float*)Cp + (size_t)gm * N + n0 + wc * 64 + l15;
#pragma unroll
        for (int n = 0; n < 4; ++n) crow[n * 16] = acc[m][n][r];
      } else {
        u16* crow = (u16*)Cp + (size_t)gm * N + n0 + wc * 64 + l15;
#pragma unroll
        for (int n = 0; n < 4; ++n) crow[n * 16] = f2bf(acc[m][n][r]);
      }
    }
}

// ---- RoPE in-place on q,k slots of qkv [B=2][T=2048][3][H=16][Dh=128] ----
__global__ __launch_bounds__(256)
void rope_kernel(u16* __restrict__ qkv, const int* __restrict__ seq_off) {
  const int idx = blockIdx.x * 256 + threadIdx.x;  // 4194304 threads
  const int d = idx & 63;
  const int h = (idx >> 6) & 15;
  const int t = (idx >> 10) & 2047;
  const int b = idx >> 21;
  const float pos = (float)(seq_off[0] + t);
  const float inv = expf((float)d * (-0.14391156509731588f));  // -ln(1e4)/64
  float sv, cv;
  sincosf(pos * inv, &sv, &cv);
  const size_t base = ((size_t)(b * 2048 + t)) * 6144 + h * 128 + d;
  const float q1 = bf2f(qkv[base]);
  const float q2 = bf2f(qkv[base + 64]);
  qkv[base] = f2bf(q1 * cv - q2 * sv);
  qkv[base + 64] = f2bf(q2 * cv + q1 * sv);
  const float k1 = bf2f(qkv[base + 2048]);
  const float k2 = bf2f(qkv[base + 2048 + 64]);
  qkv[base + 2048] = f2bf(k1 * cv - k2 * sv);
  qkv[base + 2048 + 64] = f2bf(k2 * cv + k1 * sv);
}

// ---- BRUTE-FORCE attention: one wave per (b,h,t) row (kept this round) ----
__global__ __launch_bounds__(256)
void attn_brute(const u16* __restrict__ qkv, u16* __restrict__ ctx) {
  __shared__ float p[4][2048];
  __shared__ float ql[4][128];
  const int tid = threadIdx.x, lane = tid & 63, w = tid >> 6;
  const int wg = blockIdx.x * 4 + w;       // 0..65535
  const int t = 2047 - (wg & 2047);        // long rows first
  const int h = (wg >> 11) & 15;
  const int b = wg >> 15;
  const size_t rowQ = ((size_t)(b * 2048 + t)) * 6144 + h * 128;
  const u16* Kb = qkv + (size_t)b * 2048 * 6144 + h * 128 + 2048;
  const u16* Vb = Kb + 2048;

  ql[w][lane]      = bf2f(qkv[rowQ + lane]);
  ql[w][lane + 64] = bf2f(qkv[rowQ + lane + 64]);
  asm volatile("s_waitcnt lgkmcnt(0)" ::: "memory");

  const float scale = 0.08838834764831845f;  // 1/sqrt(128)
  float mloc = -1e30f;
  for (int s0 = 0; s0 <= t; s0 += 64) {
    const int s = s0 + lane;
    if (s <= t) {
      const u16* kr = Kb + (size_t)s * 6144;
      float dot = 0.f;
      for (int d = 0; d < 128; ++d) dot += ql[w][d] * bf2f(kr[d]);
      dot *= scale;
      p[w][s] = dot;
      mloc = fmaxf(mloc, dot);
    }
  }
#pragma unroll
  for (int off = 1; off < 64; off <<= 1) mloc = fmaxf(mloc, __shfl_xor(mloc, off));
  asm volatile("s_waitcnt lgkmcnt(0)" ::: "memory");

  float lsum = 0.f;
  for (int s = lane; s <= t; s += 64) {
    const float e = __expf(p[w][s] - mloc);
    p[w][s] = e;
    lsum += e;
  }
#pragma unroll
  for (int off = 1; off < 64; off <<= 1) lsum += __shfl_xor(lsum, off);
  const float inv = 1.0f / lsum;
  asm volatile("s_waitcnt lgkmcnt(0)" ::: "memory");

  float a0 = 0.f, a1 = 0.f;
  for (int s = 0; s <= t; ++s) {
    const float pv = p[w][s];
    const u16* vr = Vb + (size_t)s * 6144;
    a0 += pv * bf2f(vr[lane]);
    a1 += pv * bf2f(vr[lane + 64]);
  }
  u16* cr = ctx + ((size_t)(b * 2048 + t)) * 2048 + h * 128;
  cr[lane]      = f2bf(a0 * inv);
  cr[lane + 64] = f2bf(a1 * inv);
}

extern "C" void kernel_launch(void* const* d_in, const int* in_sizes, int n_in,
                              void* d_out, int out_size, void* d_ws, size_t ws_size,
                              hipStream_t stream) {
  const float* x     = (const float*)d_in[0];   // (2,2048,2048) fp32
  const float* wqkv  = (const float*)d_in[1];   // (6144,2048) fp32
  const float* wproj = (const float*)d_in[2];   // (2048,2048) fp32
  const int*   soff  = (const int*)d_in[3];     // scalar int
  float* out = (float*)d_out;                   // (2,2048,2048) fp32  <-- THE FIX

  u16* qkv = (u16*)d_ws;                        // 25165824 u16 = 50.3 MB
  u16* ctx = qkv + (size_t)25165824;            //  8388608 u16 = 16.8 MB

  gemm_bt<true, true, false><<<dim3(48, 32), 256, 0, stream>>>(x, wqkv, qkv, 4096, 6144, 2048);
  rope_kernel<<<16384, 256, 0, stream>>>(qkv, soff);
  attn_brute<<<16384, 256, 0, stream>>>(qkv, ctx);
  gemm_bt<false, true, true><<<dim3(16, 32), 256, 0, stream>>>(ctx, wproj, out, 4096, 2048, 2048);
}

// Round 7
// 681.429 us; speedup vs baseline: 4.9644x; 4.9644x over previous
//
#include <hip/hip_runtime.h>
#include <math.h>

typedef __bf16 bf16x8 __attribute__((ext_vector_type(8)));
typedef float f32x4 __attribute__((ext_vector_type(4)));
typedef unsigned short u16;
typedef unsigned short u16x4 __attribute__((ext_vector_type(4)));
typedef unsigned short u16x8 __attribute__((ext_vector_type(8)));
typedef unsigned int u32;

#define AS1 __attribute__((address_space(1)))
#define AS3 __attribute__((address_space(3)))

static __device__ __forceinline__ float bf2f(u16 u) {
  union { u32 i; float f; } v; v.i = ((u32)u) << 16; return v.f;
}
static __device__ __forceinline__ u16 f2bf(float f) {
  union { float f; u32 i; } v; v.f = f;
  u32 r = v.i + 0x7FFFu + ((v.i >> 16) & 1u);
  return (u16)(r >> 16);
}

// ---- GEMM: C[M,N] = A[M,K] @ B[N,K]^T; A/B fp32 or bf16; C bf16 or fp32 ----
// 128x128 tile, BK=32, 4 waves (2x2), 16x mfma_16x16x32_bf16 per wave/K-step.
template <bool AF32, bool BF32, bool CF32>
__global__ __launch_bounds__(256, 2)
void gemm_bt(const void* __restrict__ Ap, const void* __restrict__ Bp,
             void* __restrict__ Cp, int M, int N, int K) {
  __shared__ __align__(16) u16 As[128 * 32];
  __shared__ __align__(16) u16 Bs[128 * 32];
  const int tid = threadIdx.x;
  const int lane = tid & 63;
  const int wid = tid >> 6;
  const int wr = wid >> 1, wc = wid & 1;
  const int l15 = lane & 15, l4 = lane >> 4;
  const int m0 = blockIdx.y * 128, n0 = blockIdx.x * 128;
  const float* Af = (const float*)Ap;
  const u16*   Ab = (const u16*)Ap;
  const float* Bf = (const float*)Bp;
  const u16*   Bb = (const u16*)Bp;

  const f32x4 fzero = {0.f, 0.f, 0.f, 0.f};
  f32x4 acc[4][4];
#pragma unroll
  for (int i = 0; i < 4; ++i)
#pragma unroll
    for (int j = 0; j < 4; ++j) acc[i][j] = fzero;

  for (int kt = 0; kt < K; kt += 32) {
    float4 ar[4], br[4];
    if constexpr (AF32) {
#pragma unroll
      for (int i = 0; i < 4; ++i) {
        const int q = i * 256 + tid;  // 0..1023: row=q>>3, col4=q&7
        ar[i] = *(const float4*)(Af + (size_t)(m0 + (q >> 3)) * K + kt + (q & 7) * 4);
      }
    } else {
#pragma unroll
      for (int i = 0; i < 2; ++i) {
        const int c = wid * 64 + i * 256 + lane;  // 0..511: row=c>>2, col8=c&3
        const u16* ga = Ab + (size_t)(m0 + (c >> 2)) * K + kt + (c & 3) * 8;
        __builtin_amdgcn_global_load_lds((AS1 void*)ga,
            (AS3 void*)(As + (size_t)(wid * 64 + i * 256) * 8), 16, 0, 0);
      }
    }
    if constexpr (BF32) {
#pragma unroll
      for (int i = 0; i < 4; ++i) {
        const int q = i * 256 + tid;
        br[i] = *(const float4*)(Bf + (size_t)(n0 + (q >> 3)) * K + kt + (q & 7) * 4);
      }
    } else {
#pragma unroll
      for (int i = 0; i < 2; ++i) {
        const int c = wid * 64 + i * 256 + lane;
        const u16* gb = Bb + (size_t)(n0 + (c >> 2)) * K + kt + (c & 3) * 8;
        __builtin_amdgcn_global_load_lds((AS1 void*)gb,
            (AS3 void*)(Bs + (size_t)(wid * 64 + i * 256) * 8), 16, 0, 0);
      }
    }
    __syncthreads();
    if constexpr (AF32) {
#pragma unroll
      for (int i = 0; i < 4; ++i) {
        const int q = i * 256 + tid;
        u16x4 p = {f2bf(ar[i].x), f2bf(ar[i].y), f2bf(ar[i].z), f2bf(ar[i].w)};
        *(u16x4*)&As[(q >> 3) * 32 + (q & 7) * 4] = p;
      }
    }
    if constexpr (BF32) {
#pragma unroll
      for (int i = 0; i < 4; ++i) {
        const int q = i * 256 + tid;
        u16x4 p = {f2bf(br[i].x), f2bf(br[i].y), f2bf(br[i].z), f2bf(br[i].w)};
        *(u16x4*)&Bs[(q >> 3) * 32 + (q & 7) * 4] = p;
      }
    }
    if constexpr (AF32 || BF32) __syncthreads();
    bf16x8 af[4], bfr[4];
#pragma unroll
    for (int m = 0; m < 4; ++m)
      af[m] = *(const bf16x8*)&As[(wr * 64 + m * 16 + l15) * 32 + l4 * 8];
#pragma unroll
    for (int n = 0; n < 4; ++n)
      bfr[n] = *(const bf16x8*)&Bs[(wc * 64 + n * 16 + l15) * 32 + l4 * 8];
#pragma unroll
    for (int m = 0; m < 4; ++m)
#pragma unroll
      for (int n = 0; n < 4; ++n)
        acc[m][n] = __builtin_amdgcn_mfma_f32_16x16x32_bf16(af[m], bfr[n], acc[m][n], 0, 0, 0);
    if constexpr (!AF32 || !BF32) __syncthreads();
  }

  // C/D: row=(lane>>4)*4+r, col=lane&15
#pragma unroll
  for (int m = 0; m < 4; ++m)
#pragma unroll
    for (int r = 0; r < 4; ++r) {
      const int gm = m0 + wr * 64 + m * 16 + l4 * 4 + r;
      if constexpr (CF32) {
        float* crow = (float*)Cp + (size_t)gm * N + n0 + wc * 64 + l15;
#pragma unroll
        for (int n = 0; n < 4; ++n) crow[n * 16] = acc[m][n][r];
      } else {
        u16* crow = (u16*)Cp + (size_t)gm * N + n0 + wc * 64 + l15;
#pragma unroll
        for (int n = 0; n < 4; ++n) crow[n * 16] = f2bf(acc[m][n][r]);
      }
    }
}

// ---- RoPE in-place on q,k slots of qkv [B=2][T=2048][3][H=16][Dh=128] ----
__global__ __launch_bounds__(256)
void rope_kernel(u16* __restrict__ qkv, const int* __restrict__ seq_off) {
  const int idx = blockIdx.x * 256 + threadIdx.x;  // 4194304 threads
  const int d = idx & 63;
  const int h = (idx >> 6) & 15;
  const int t = (idx >> 10) & 2047;
  const int b = idx >> 21;
  const float pos = (float)(seq_off[0] + t);
  const float inv = expf((float)d * (-0.14391156509731588f));  // -ln(1e4)/64
  float sv, cv;
  sincosf(pos * inv, &sv, &cv);
  const size_t base = ((size_t)(b * 2048 + t)) * 6144 + h * 128 + d;
  const float q1 = bf2f(qkv[base]);
  const float q2 = bf2f(qkv[base + 64]);
  qkv[base] = f2bf(q1 * cv - q2 * sv);
  qkv[base + 64] = f2bf(q2 * cv + q1 * sv);
  const float k1 = bf2f(qkv[base + 2048]);
  const float k2 = bf2f(qkv[base + 2048 + 64]);
  qkv[base + 2048] = f2bf(k1 * cv - k2 * sv);
  qkv[base + 2048 + 64] = f2bf(k2 * cv + k1 * sv);
}

// ---- Flash attention, causal. 4 waves/block, 16 q-rows each. ----
// Uniform trip count across waves (extra tiles fully masked -> exact no-ops)
// so __syncthreads() is legal; 2 barriers per KV tile.
__global__ __launch_bounds__(256, 2)
void attn_kernel(const u16* __restrict__ qkv, u16* __restrict__ ctx) {
  __shared__ __align__(16) u16 Plds[4][16 * 32];  // per-wave P (16q x 32kv)
  __shared__ __align__(16) u16 Vt[4][128 * 40];   // per-wave V^T (dh x kv, stride 40)
  const int tid = threadIdx.x, lane = tid & 63, w = tid >> 6;
  const int l15 = lane & 15, l4 = lane >> 4;
  const int bh = blockIdx.x;
  const int qt = gridDim.y - 1 - blockIdx.y;      // longest blocks first
  const int b = bh >> 4, h = bh & 15;
  const int q0 = qt * 64 + w * 16;
  const u16* Qb = qkv + (size_t)b * 2048 * 6144 + h * 128;
  const u16* Kb = Qb + 2048;
  const u16* Vb = Qb + 4096;

  bf16x8 qf[4];
#pragma unroll
  for (int c = 0; c < 4; ++c)
    qf[c] = *(const bf16x8*)(Qb + (size_t)(q0 + l15) * 6144 + c * 32 + l4 * 8);

  const f32x4 fzero = {0.f, 0.f, 0.f, 0.f};
  f32x4 o[8];
#pragma unroll
  for (int ch = 0; ch < 8; ++ch) o[ch] = fzero;
  const float NEG = -1e30f;
  float mrow[4] = {NEG, NEG, NEG, NEG};
  float lrow[4] = {0.f, 0.f, 0.f, 0.f};

  const float scale = 0.08838834764831845f;  // 1/sqrt(128)
  const int nt_blk = qt * 2 + 2;  // uniform for all 4 waves
  for (int kt = 0; kt < nt_blk; ++kt) {
    const int kv0 = kt * 32;
    f32x4 s0 = fzero, s1 = fzero;
#pragma unroll
    for (int c = 0; c < 4; ++c) {
      const bf16x8 kf = *(const bf16x8*)(Kb + (size_t)(kv0 + l15) * 6144 + c * 32 + l4 * 8);
      s0 = __builtin_amdgcn_mfma_f32_16x16x32_bf16(qf[c], kf, s0, 0, 0, 0);
    }
#pragma unroll
    for (int c = 0; c < 4; ++c) {
      const bf16x8 kf = *(const bf16x8*)(Kb + (size_t)(kv0 + 16 + l15) * 6144 + c * 32 + l4 * 8);
      s1 = __builtin_amdgcn_mfma_f32_16x16x32_bf16(qf[c], kf, s1, 0, 0, 0);
    }
    __syncthreads();  // WAR: everyone's prior PV ds_reads complete
    // stage V^T: Vt[dh][kv], pair-packed u32 writes (kv pairs r0,r0+1)
#pragma unroll
    for (int it = 0; it < 2; ++it) {
      const int r0 = it * 16 + (lane >> 3) * 2;
      const int dh0 = (lane & 7) * 16;
      const u16* vp = Vb + (size_t)(kv0 + r0) * 6144 + dh0;
      const u16x8 v0a = *(const u16x8*)(vp);
      const u16x8 v0b = *(const u16x8*)(vp + 8);
      const u16x8 v1a = *(const u16x8*)(vp + 6144);
      const u16x8 v1b = *(const u16x8*)(vp + 6144 + 8);
#pragma unroll
      for (int e = 0; e < 8; ++e) {
        *(u32*)&Vt[w][(dh0 + e) * 40 + r0] = (u32)v0a[e] | ((u32)v1a[e] << 16);
        *(u32*)&Vt[w][(dh0 + 8 + e) * 40 + r0] = (u32)v0b[e] | ((u32)v1b[e] << 16);
      }
    }
    // online softmax; S: row=(l>>4)*4+r (q), col=l&15 (kv)
    float alpha[4];
#pragma unroll
    for (int r = 0; r < 4; ++r) {
      const int qg = q0 + l4 * 4 + r;
      const float sv0 = (kv0 + l15 <= qg) ? s0[r] * scale : NEG;
      const float sv1 = (kv0 + 16 + l15 <= qg) ? s1[r] * scale : NEG;
      float tm = fmaxf(sv0, sv1);
      tm = fmaxf(tm, __shfl_xor(tm, 1));
      tm = fmaxf(tm, __shfl_xor(tm, 2));
      tm = fmaxf(tm, __shfl_xor(tm, 4));
      tm = fmaxf(tm, __shfl_xor(tm, 8));
      const float mnew = fmaxf(mrow[r], tm);  // fully-masked tile: mnew=mrow
      alpha[r] = __expf(mrow[r] - mnew);
      const float p0 = __expf(sv0 - mnew);
      const float p1 = __expf(sv1 - mnew);
      float ps = p0 + p1;
      ps += __shfl_xor(ps, 1);
      ps += __shfl_xor(ps, 2);
      ps += __shfl_xor(ps, 4);
      ps += __shfl_xor(ps, 8);
      lrow[r] = lrow[r] * alpha[r] + ps;
      mrow[r] = mnew;
      Plds[w][(l4 * 4 + r) * 32 + l15] = f2bf(p0);
      Plds[w][(l4 * 4 + r) * 32 + 16 + l15] = f2bf(p1);
    }
    __syncthreads();  // RAW: Vt/Plds writes visible before PV reads
#pragma unroll
    for (int ch = 0; ch < 8; ++ch) {
      o[ch][0] *= alpha[0]; o[ch][1] *= alpha[1];
      o[ch][2] *= alpha[2]; o[ch][3] *= alpha[3];
    }
    const bf16x8 pa = *(const bf16x8*)&Plds[w][l15 * 32 + l4 * 8];
#pragma unroll
    for (int ch = 0; ch < 8; ++ch) {
      const bf16x8 vbf = *(const bf16x8*)&Vt[w][(ch * 16 + l15) * 40 + l4 * 8];
      o[ch] = __builtin_amdgcn_mfma_f32_16x16x32_bf16(pa, vbf, o[ch], 0, 0, 0);
    }
  }
  float invl[4];
#pragma unroll
  for (int r = 0; r < 4; ++r) invl[r] = 1.0f / lrow[r];
#pragma unroll
  for (int ch = 0; ch < 8; ++ch)
#pragma unroll
    for (int r = 0; r < 4; ++r) {
      const int gq = q0 + l4 * 4 + r;
      ctx[(size_t)(b * 2048 + gq) * 2048 + h * 128 + ch * 16 + l15] =
          f2bf(o[ch][r] * invl[r]);
    }
}

extern "C" void kernel_launch(void* const* d_in, const int* in_sizes, int n_in,
                              void* d_out, int out_size, void* d_ws, size_t ws_size,
                              hipStream_t stream) {
  const float* x     = (const float*)d_in[0];   // (2,2048,2048) fp32
  const float* wqkv  = (const float*)d_in[1];   // (6144,2048) fp32
  const float* wproj = (const float*)d_in[2];   // (2048,2048) fp32
  const int*   soff  = (const int*)d_in[3];     // scalar int
  float* out = (float*)d_out;                   // (2,2048,2048) fp32

  u16* qkv = (u16*)d_ws;                        // 25165824 u16 = 50.3 MB
  u16* ctx = qkv + (size_t)25165824;            //  8388608 u16 = 16.8 MB

  gemm_bt<true, true, false><<<dim3(48, 32), 256, 0, stream>>>(x, wqkv, qkv, 4096, 6144, 2048);
  rope_kernel<<<16384, 256, 0, stream>>>(qkv, soff);
  attn_kernel<<<dim3(32, 32), 256, 0, stream>>>(qkv, ctx);
  gemm_bt<false, true, true><<<dim3(16, 32), 256, 0, stream>>>(ctx, wproj, out, 4096, 2048, 2048);
}

// Round 8
// 443.758 us; speedup vs baseline: 7.6233x; 1.5356x over previous
//
#include <hip/hip_runtime.h>
#include <math.h>

typedef __bf16 bf16x8 __attribute__((ext_vector_type(8)));
typedef float f32x4 __attribute__((ext_vector_type(4)));
typedef unsigned short u16;
typedef unsigned short u16x4 __attribute__((ext_vector_type(4)));
typedef unsigned short u16x8 __attribute__((ext_vector_type(8)));
typedef unsigned int u32;

#define AS1 __attribute__((address_space(1)))
#define AS3 __attribute__((address_space(3)))

static __device__ __forceinline__ float bf2f(u16 u) {
  union { u32 i; float f; } v; v.i = ((u32)u) << 16; return v.f;
}
static __device__ __forceinline__ u16 f2bf(float f) {
  union { float f; u32 i; } v; v.f = f;
  u32 r = v.i + 0x7FFFu + ((v.i >> 16) & 1u);
  return (u16)(r >> 16);
}

// ---- one-shot fp32 -> bf16 convert (memory-bound, coalesced) ----
__global__ __launch_bounds__(256)
void f32_to_bf16(const float* __restrict__ src, u16* __restrict__ dst, int n4) {
  const int gid = blockIdx.x * 256 + threadIdx.x;
  if (gid >= n4) return;
  const float4 v = ((const float4*)src)[gid];
  u16x4 p = {f2bf(v.x), f2bf(v.y), f2bf(v.z), f2bf(v.w)};
  ((u16x4*)dst)[gid] = p;
}

// ---- GEMM: C[M,N] = A[M,K] @ B[N,K]^T, bf16 A/B via global_load_lds ----
// m97 structure: 128x128 tile, BK=32, 4 waves (2x2), 2 barriers/K-step,
// 16x mfma_16x16x32_bf16 per wave per K-step. C bf16 or fp32.
template <bool CF32>
__global__ __launch_bounds__(256, 2)
void gemm_bt(const u16* __restrict__ A, const u16* __restrict__ B,
             void* __restrict__ Cp, int M, int N, int K) {
  __shared__ __align__(16) u16 As[128 * 32];
  __shared__ __align__(16) u16 Bs[128 * 32];
  const int tid = threadIdx.x;
  const int lane = tid & 63;
  const int wid = tid >> 6;
  const int wr = wid >> 1, wc = wid & 1;
  const int l15 = lane & 15, l4 = lane >> 4;
  const int m0 = blockIdx.y * 128, n0 = blockIdx.x * 128;

  const f32x4 fzero = {0.f, 0.f, 0.f, 0.f};
  f32x4 acc[4][4];
#pragma unroll
  for (int i = 0; i < 4; ++i)
#pragma unroll
    for (int j = 0; j < 4; ++j) acc[i][j] = fzero;

  for (int kt = 0; kt < K; kt += 32) {
    // stage A,B tiles: chunk c (0..511) -> row c>>2, col8 c&3; LDS linear
#pragma unroll
    for (int i = 0; i < 2; ++i) {
      const int c = wid * 64 + i * 256 + lane;
      const u16* ga = A + (size_t)(m0 + (c >> 2)) * K + kt + (c & 3) * 8;
      const u16* gb = B + (size_t)(n0 + (c >> 2)) * K + kt + (c & 3) * 8;
      __builtin_amdgcn_global_load_lds((AS1 void*)ga,
          (AS3 void*)(As + (size_t)(wid * 64 + i * 256) * 8), 16, 0, 0);
      __builtin_amdgcn_global_load_lds((AS1 void*)gb,
          (AS3 void*)(Bs + (size_t)(wid * 64 + i * 256) * 8), 16, 0, 0);
    }
    __syncthreads();  // drains vmcnt: staged data visible
    bf16x8 af[4], bfr[4];
#pragma unroll
    for (int m = 0; m < 4; ++m)
      af[m] = *(const bf16x8*)&As[(wr * 64 + m * 16 + l15) * 32 + l4 * 8];
#pragma unroll
    for (int n = 0; n < 4; ++n)
      bfr[n] = *(const bf16x8*)&Bs[(wc * 64 + n * 16 + l15) * 32 + l4 * 8];
#pragma unroll
    for (int m = 0; m < 4; ++m)
#pragma unroll
      for (int n = 0; n < 4; ++n)
        acc[m][n] = __builtin_amdgcn_mfma_f32_16x16x32_bf16(af[m], bfr[n], acc[m][n], 0, 0, 0);
    __syncthreads();  // reads done before next iter's async stores land
  }

  // C/D: row=(lane>>4)*4+r, col=lane&15
#pragma unroll
  for (int m = 0; m < 4; ++m)
#pragma unroll
    for (int r = 0; r < 4; ++r) {
      const int gm = m0 + wr * 64 + m * 16 + l4 * 4 + r;
      if constexpr (CF32) {
        float* crow = (float*)Cp + (size_t)gm * N + n0 + wc * 64 + l15;
#pragma unroll
        for (int n = 0; n < 4; ++n) crow[n * 16] = acc[m][n][r];
      } else {
        u16* crow = (u16*)Cp + (size_t)gm * N + n0 + wc * 64 + l15;
#pragma unroll
        for (int n = 0; n < 4; ++n) crow[n * 16] = f2bf(acc[m][n][r]);
      }
    }
}

// ---- RoPE in-place on q,k slots of qkv [B=2][T=2048][3][H=16][Dh=128] ----
__global__ __launch_bounds__(256)
void rope_kernel(u16* __restrict__ qkv, const int* __restrict__ seq_off) {
  const int idx = blockIdx.x * 256 + threadIdx.x;  // 4194304 threads
  const int d = idx & 63;
  const int h = (idx >> 6) & 15;
  const int t = (idx >> 10) & 2047;
  const int b = idx >> 21;
  const float pos = (float)(seq_off[0] + t);
  const float inv = expf((float)d * (-0.14391156509731588f));  // -ln(1e4)/64
  float sv, cv;
  sincosf(pos * inv, &sv, &cv);
  const size_t base = ((size_t)(b * 2048 + t)) * 6144 + h * 128 + d;
  const float q1 = bf2f(qkv[base]);
  const float q2 = bf2f(qkv[base + 64]);
  qkv[base] = f2bf(q1 * cv - q2 * sv);
  qkv[base + 64] = f2bf(q2 * cv + q1 * sv);
  const float k1 = bf2f(qkv[base + 2048]);
  const float k2 = bf2f(qkv[base + 2048 + 64]);
  qkv[base + 2048] = f2bf(k1 * cv - k2 * sv);
  qkv[base + 2048 + 64] = f2bf(k2 * cv + k1 * sv);
}

// ---- Flash attention, causal. 4 waves/block, 16 q-rows each. ----
__global__ __launch_bounds__(256, 2)
void attn_kernel(const u16* __restrict__ qkv, u16* __restrict__ ctx) {
  __shared__ __align__(16) u16 Plds[4][16 * 32];  // per-wave P (16q x 32kv)
  __shared__ __align__(16) u16 Vt[4][128 * 40];   // per-wave V^T (dh x kv, stride 40)
  const int tid = threadIdx.x, lane = tid & 63, w = tid >> 6;
  const int l15 = lane & 15, l4 = lane >> 4;
  const int bh = blockIdx.x;
  const int qt = gridDim.y - 1 - blockIdx.y;      // longest blocks first
  const int b = bh >> 4, h = bh & 15;
  const int q0 = qt * 64 + w * 16;
  const u16* Qb = qkv + (size_t)b * 2048 * 6144 + h * 128;
  const u16* Kb = Qb + 2048;
  const u16* Vb = Qb + 4096;

  bf16x8 qf[4];
#pragma unroll
  for (int c = 0; c < 4; ++c)
    qf[c] = *(const bf16x8*)(Qb + (size_t)(q0 + l15) * 6144 + c * 32 + l4 * 8);

  const f32x4 fzero = {0.f, 0.f, 0.f, 0.f};
  f32x4 o[8];
#pragma unroll
  for (int ch = 0; ch < 8; ++ch) o[ch] = fzero;
  const float NEG = -1e30f;
  float mrow[4] = {NEG, NEG, NEG, NEG};
  float lrow[4] = {0.f, 0.f, 0.f, 0.f};

  const float scale = 0.08838834764831845f;  // 1/sqrt(128)
  const int nt_blk = qt * 2 + 2;  // uniform for all 4 waves
  for (int kt = 0; kt < nt_blk; ++kt) {
    const int kv0 = kt * 32;
    f32x4 s0 = fzero, s1 = fzero;
#pragma unroll
    for (int c = 0; c < 4; ++c) {
      const bf16x8 kf = *(const bf16x8*)(Kb + (size_t)(kv0 + l15) * 6144 + c * 32 + l4 * 8);
      s0 = __builtin_amdgcn_mfma_f32_16x16x32_bf16(qf[c], kf, s0, 0, 0, 0);
    }
#pragma unroll
    for (int c = 0; c < 4; ++c) {
      const bf16x8 kf = *(const bf16x8*)(Kb + (size_t)(kv0 + 16 + l15) * 6144 + c * 32 + l4 * 8);
      s1 = __builtin_amdgcn_mfma_f32_16x16x32_bf16(qf[c], kf, s1, 0, 0, 0);
    }
    __syncthreads();  // WAR: everyone's prior PV ds_reads complete
#pragma unroll
    for (int it = 0; it < 2; ++it) {
      const int r0 = it * 16 + (lane >> 3) * 2;
      const int dh0 = (lane & 7) * 16;
      const u16* vp = Vb + (size_t)(kv0 + r0) * 6144 + dh0;
      const u16x8 v0a = *(const u16x8*)(vp);
      const u16x8 v0b = *(const u16x8*)(vp + 8);
      const u16x8 v1a = *(const u16x8*)(vp + 6144);
      const u16x8 v1b = *(const u16x8*)(vp + 6144 + 8);
#pragma unroll
      for (int e = 0; e < 8; ++e) {
        *(u32*)&Vt[w][(dh0 + e) * 40 + r0] = (u32)v0a[e] | ((u32)v1a[e] << 16);
        *(u32*)&Vt[w][(dh0 + 8 + e) * 40 + r0] = (u32)v0b[e] | ((u32)v1b[e] << 16);
      }
    }
    float alpha[4];
#pragma unroll
    for (int r = 0; r < 4; ++r) {
      const int qg = q0 + l4 * 4 + r;
      const float sv0 = (kv0 + l15 <= qg) ? s0[r] * scale : NEG;
      const float sv1 = (kv0 + 16 + l15 <= qg) ? s1[r] * scale : NEG;
      float tm = fmaxf(sv0, sv1);
      tm = fmaxf(tm, __shfl_xor(tm, 1));
      tm = fmaxf(tm, __shfl_xor(tm, 2));
      tm = fmaxf(tm, __shfl_xor(tm, 4));
      tm = fmaxf(tm, __shfl_xor(tm, 8));
      const float mnew = fmaxf(mrow[r], tm);
      alpha[r] = __expf(mrow[r] - mnew);
      const float p0 = __expf(sv0 - mnew);
      const float p1 = __expf(sv1 - mnew);
      float ps = p0 + p1;
      ps += __shfl_xor(ps, 1);
      ps += __shfl_xor(ps, 2);
      ps += __shfl_xor(ps, 4);
      ps += __shfl_xor(ps, 8);
      lrow[r] = lrow[r] * alpha[r] + ps;
      mrow[r] = mnew;
      Plds[w][(l4 * 4 + r) * 32 + l15] = f2bf(p0);
      Plds[w][(l4 * 4 + r) * 32 + 16 + l15] = f2bf(p1);
    }
    __syncthreads();  // RAW: Vt/Plds writes visible before PV reads
#pragma unroll
    for (int ch = 0; ch < 8; ++ch) {
      o[ch][0] *= alpha[0]; o[ch][1] *= alpha[1];
      o[ch][2] *= alpha[2]; o[ch][3] *= alpha[3];
    }
    const bf16x8 pa = *(const bf16x8*)&Plds[w][l15 * 32 + l4 * 8];
#pragma unroll
    for (int ch = 0; ch < 8; ++ch) {
      const bf16x8 vbf = *(const bf16x8*)&Vt[w][(ch * 16 + l15) * 40 + l4 * 8];
      o[ch] = __builtin_amdgcn_mfma_f32_16x16x32_bf16(pa, vbf, o[ch], 0, 0, 0);
    }
  }
  float invl[4];
#pragma unroll
  for (int r = 0; r < 4; ++r) invl[r] = 1.0f / lrow[r];
#pragma unroll
  for (int ch = 0; ch < 8; ++ch)
#pragma unroll
    for (int r = 0; r < 4; ++r) {
      const int gq = q0 + l4 * 4 + r;
      ctx[(size_t)(b * 2048 + gq) * 2048 + h * 128 + ch * 16 + l15] =
          f2bf(o[ch][r] * invl[r]);
    }
}

extern "C" void kernel_launch(void* const* d_in, const int* in_sizes, int n_in,
                              void* d_out, int out_size, void* d_ws, size_t ws_size,
                              hipStream_t stream) {
  const float* x     = (const float*)d_in[0];   // (2,2048,2048) fp32
  const float* wqkv  = (const float*)d_in[1];   // (6144,2048) fp32
  const float* wproj = (const float*)d_in[2];   // (2048,2048) fp32
  const int*   soff  = (const int*)d_in[3];     // scalar int
  float* out = (float*)d_out;                   // (2,2048,2048) fp32

  // ws layout (u16 units), total 100.7 MB:
  u16* wsu    = (u16*)d_ws;
  u16* xb     = wsu;                    //  8388608 u16 (dead after gemm1)
  u16* wqkvb  = xb + 8388608;           // 12582912 u16
  u16* wprojb = wqkvb + 12582912;       //  4194304 u16
  u16* qkv    = wprojb + 4194304;       // 25165824 u16
  u16* ctx    = xb;                     // reuse xb region

  f32_to_bf16<<<8192, 256, 0, stream>>>(x, xb, 2097152);
  f32_to_bf16<<<12288, 256, 0, stream>>>(wqkv, wqkvb, 3145728);
  f32_to_bf16<<<4096, 256, 0, stream>>>(wproj, wprojb, 1048576);

  gemm_bt<false><<<dim3(48, 32), 256, 0, stream>>>(xb, wqkvb, qkv, 4096, 6144, 2048);
  rope_kernel<<<16384, 256, 0, stream>>>(qkv, soff);
  attn_kernel<<<dim3(32, 32), 256, 0, stream>>>(qkv, ctx);
  gemm_bt<true><<<dim3(16, 32), 256, 0, stream>>>(ctx, wprojb, out, 4096, 2048, 2048);
}

// Round 9
// 427.898 us; speedup vs baseline: 7.9058x; 1.0371x over previous
//
#include <hip/hip_runtime.h>
#include <math.h>

typedef __bf16 bf16x8 __attribute__((ext_vector_type(8)));
typedef float f32x4 __attribute__((ext_vector_type(4)));
typedef unsigned short u16;
typedef unsigned short u16x4 __attribute__((ext_vector_type(4)));
typedef unsigned short u16x8 __attribute__((ext_vector_type(8)));
typedef unsigned int u32;

#define AS1 __attribute__((address_space(1)))
#define AS3 __attribute__((address_space(3)))

static __device__ __forceinline__ float bf2f(u16 u) {
  union { u32 i; float f; } v; v.i = ((u32)u) << 16; return v.f;
}
static __device__ __forceinline__ u16 f2bf(float f) {
  union { float f; u32 i; } v; v.f = f;
  u32 r = v.i + 0x7FFFu + ((v.i >> 16) & 1u);
  return (u16)(r >> 16);
}

// ---- one-shot fp32 -> bf16 convert (memory-bound, coalesced) ----
__global__ __launch_bounds__(256)
void f32_to_bf16(const float* __restrict__ src, u16* __restrict__ dst, int n4) {
  const int gid = blockIdx.x * 256 + threadIdx.x;
  if (gid >= n4) return;
  const float4 v = ((const float4*)src)[gid];
  u16x4 p = {f2bf(v.x), f2bf(v.y), f2bf(v.z), f2bf(v.w)};
  ((u16x4*)dst)[gid] = p;
}

// ---- GEMM: C[M,N] = A[M,K] @ B[N,K]^T, bf16 A/B via global_load_lds ----
// m97 structure: 128x128 tile, BK=32, 4 waves (2x2), 2 barriers/K-step.
template <bool CF32>
__global__ __launch_bounds__(256, 2)
void gemm_bt(const u16* __restrict__ A, const u16* __restrict__ B,
             void* __restrict__ Cp, int M, int N, int K) {
  __shared__ __align__(16) u16 As[128 * 32];
  __shared__ __align__(16) u16 Bs[128 * 32];
  const int tid = threadIdx.x;
  const int lane = tid & 63;
  const int wid = tid >> 6;
  const int wr = wid >> 1, wc = wid & 1;
  const int l15 = lane & 15, l4 = lane >> 4;
  const int m0 = blockIdx.y * 128, n0 = blockIdx.x * 128;

  const f32x4 fzero = {0.f, 0.f, 0.f, 0.f};
  f32x4 acc[4][4];
#pragma unroll
  for (int i = 0; i < 4; ++i)
#pragma unroll
    for (int j = 0; j < 4; ++j) acc[i][j] = fzero;

  for (int kt = 0; kt < K; kt += 32) {
#pragma unroll
    for (int i = 0; i < 2; ++i) {
      const int c = wid * 64 + i * 256 + lane;
      const u16* ga = A + (size_t)(m0 + (c >> 2)) * K + kt + (c & 3) * 8;
      const u16* gb = B + (size_t)(n0 + (c >> 2)) * K + kt + (c & 3) * 8;
      __builtin_amdgcn_global_load_lds((AS1 void*)ga,
          (AS3 void*)(As + (size_t)(wid * 64 + i * 256) * 8), 16, 0, 0);
      __builtin_amdgcn_global_load_lds((AS1 void*)gb,
          (AS3 void*)(Bs + (size_t)(wid * 64 + i * 256) * 8), 16, 0, 0);
    }
    __syncthreads();
    bf16x8 af[4], bfr[4];
#pragma unroll
    for (int m = 0; m < 4; ++m)
      af[m] = *(const bf16x8*)&As[(wr * 64 + m * 16 + l15) * 32 + l4 * 8];
#pragma unroll
    for (int n = 0; n < 4; ++n)
      bfr[n] = *(const bf16x8*)&Bs[(wc * 64 + n * 16 + l15) * 32 + l4 * 8];
#pragma unroll
    for (int m = 0; m < 4; ++m)
#pragma unroll
      for (int n = 0; n < 4; ++n)
        acc[m][n] = __builtin_amdgcn_mfma_f32_16x16x32_bf16(af[m], bfr[n], acc[m][n], 0, 0, 0);
    __syncthreads();
  }

#pragma unroll
  for (int m = 0; m < 4; ++m)
#pragma unroll
    for (int r = 0; r < 4; ++r) {
      const int gm = m0 + wr * 64 + m * 16 + l4 * 4 + r;
      if constexpr (CF32) {
        float* crow = (float*)Cp + (size_t)gm * N + n0 + wc * 64 + l15;
#pragma unroll
        for (int n = 0; n < 4; ++n) crow[n * 16] = acc[m][n][r];
      } else {
        u16* crow = (u16*)Cp + (size_t)gm * N + n0 + wc * 64 + l15;
#pragma unroll
        for (int n = 0; n < 4; ++n) crow[n * 16] = f2bf(acc[m][n][r]);
      }
    }
}

// ---- RoPE in-place on q,k slots of qkv [B=2][T=2048][3][H=16][Dh=128] ----
__global__ __launch_bounds__(256)
void rope_kernel(u16* __restrict__ qkv, const int* __restrict__ seq_off) {
  const int idx = blockIdx.x * 256 + threadIdx.x;  // 4194304 threads
  const int d = idx & 63;
  const int h = (idx >> 6) & 15;
  const int t = (idx >> 10) & 2047;
  const int b = idx >> 21;
  const float pos = (float)(seq_off[0] + t);
  const float inv = expf((float)d * (-0.14391156509731588f));  // -ln(1e4)/64
  float sv, cv;
  sincosf(pos * inv, &sv, &cv);
  const size_t base = ((size_t)(b * 2048 + t)) * 6144 + h * 128 + d;
  const float q1 = bf2f(qkv[base]);
  const float q2 = bf2f(qkv[base + 64]);
  qkv[base] = f2bf(q1 * cv - q2 * sv);
  qkv[base + 64] = f2bf(q2 * cv + q1 * sv);
  const float k1 = bf2f(qkv[base + 2048]);
  const float k2 = bf2f(qkv[base + 2048 + 64]);
  qkv[base + 2048] = f2bf(k1 * cv - k2 * sv);
  qkv[base + 2048 + 64] = f2bf(k2 * cv + k1 * sv);
}

// ---- Flash attention, causal. 4 waves/block, 16 q-rows each. ----
// V^T staged ONCE per block (shared, XOR-swizzled: writes 2-way, reads
// balanced); P per-wave swizzled. Uniform trip count -> __syncthreads legal.
__global__ __launch_bounds__(256, 4)
void attn_kernel(const u16* __restrict__ qkv, u16* __restrict__ ctx) {
  __shared__ __align__(16) u16 VtS[128 * 32];      // shared swizzled V^T (8KB)
  __shared__ __align__(16) u16 Plds[4][16 * 32];   // per-wave swizzled P (4KB)
  const int tid = threadIdx.x, lane = tid & 63, w = tid >> 6;
  const int l15 = lane & 15, l4 = lane >> 4;
  const int bh = blockIdx.x;
  const int qt = gridDim.y - 1 - blockIdx.y;       // longest blocks first
  const int b = bh >> 4, h = bh & 15;
  const int q0 = qt * 64 + w * 16;
  const u16* Qb = qkv + (size_t)b * 2048 * 6144 + h * 128;
  const u16* Kb = Qb + 2048;
  const u16* Vb = Qb + 4096;

  // cooperative V-staging ids: thread -> (kv pair sp, dh block sB)
  const int sp = tid & 15;                  // kv pair 0..15
  const int sB = tid >> 4;                  // dh block 0..15 (8 dh each)
  const int sgp = sB & 1;                   // store-order parity twist
  const int swg = (((sp >> 2) ^ (sB & 3)) << 3) + ((sp & 3) << 1);

  bf16x8 qf[4];
#pragma unroll
  for (int c = 0; c < 4; ++c)
    qf[c] = *(const bf16x8*)(Qb + (size_t)(q0 + l15) * 6144 + c * 32 + l4 * 8);

  const f32x4 fzero = {0.f, 0.f, 0.f, 0.f};
  f32x4 o[8];
#pragma unroll
  for (int ch = 0; ch < 8; ++ch) o[ch] = fzero;
  const float NEG = -1e30f;
  float mrow[4] = {NEG, NEG, NEG, NEG};
  float lrow[4] = {0.f, 0.f, 0.f, 0.f};

  const float scale = 0.08838834764831845f;  // 1/sqrt(128)
  const int nt_blk = qt * 2 + 2;  // uniform for all 4 waves
  for (int kt = 0; kt < nt_blk; ++kt) {
    const int kv0 = kt * 32;
    f32x4 s0 = fzero, s1 = fzero;
#pragma unroll
    for (int c = 0; c < 4; ++c) {
      const bf16x8 kf = *(const bf16x8*)(Kb + (size_t)(kv0 + l15) * 6144 + c * 32 + l4 * 8);
      s0 = __builtin_amdgcn_mfma_f32_16x16x32_bf16(qf[c], kf, s0, 0, 0, 0);
    }
#pragma unroll
    for (int c = 0; c < 4; ++c) {
      const bf16x8 kf = *(const bf16x8*)(Kb + (size_t)(kv0 + 16 + l15) * 6144 + c * 32 + l4 * 8);
      s1 = __builtin_amdgcn_mfma_f32_16x16x32_bf16(qf[c], kf, s1, 0, 0, 0);
    }
    __syncthreads();  // WAR: all PV ds_reads of prior tile complete
    // cooperative swizzled V^T staging: thread writes 8 u32 (2-way banks)
    {
      const u16* vp0 = Vb + (size_t)(kv0 + 2 * sp) * 6144 + 8 * sB;
      const u16x8 v0 = *(const u16x8*)vp0;
      const u16x8 v1 = *(const u16x8*)(vp0 + 6144);
#pragma unroll
      for (int e = 0; e < 8; ++e) {
        const int s = e ^ sgp;
        const int dh = 8 * sB + s;
        *(u32*)&VtS[dh * 32 + swg] = (u32)v0[s] | ((u32)v1[s] << 16);
      }
    }
    // online softmax; S: row=(l>>4)*4+r (q), col=l&15 (kv)
    float alpha[4];
#pragma unroll
    for (int r = 0; r < 4; ++r) {
      const int qg = q0 + l4 * 4 + r;
      const float sv0 = (kv0 + l15 <= qg) ? s0[r] * scale : NEG;
      const float sv1 = (kv0 + 16 + l15 <= qg) ? s1[r] * scale : NEG;
      float tm = fmaxf(sv0, sv1);
      tm = fmaxf(tm, __shfl_xor(tm, 1));
      tm = fmaxf(tm, __shfl_xor(tm, 2));
      tm = fmaxf(tm, __shfl_xor(tm, 4));
      tm = fmaxf(tm, __shfl_xor(tm, 8));
      const float mnew = fmaxf(mrow[r], tm);
      alpha[r] = __expf(mrow[r] - mnew);
      const float p0 = __expf(sv0 - mnew);
      const float p1 = __expf(sv1 - mnew);
      float ps = p0 + p1;
      ps += __shfl_xor(ps, 1);
      ps += __shfl_xor(ps, 2);
      ps += __shfl_xor(ps, 4);
      ps += __shfl_xor(ps, 8);
      lrow[r] = lrow[r] * alpha[r] + ps;
      mrow[r] = mnew;
      // swizzled P write: row-major [16][32], 16B-group ^= row>>2 (=l4)
      const int row = l4 * 4 + r;
      const int g0 = ((l15 >> 3) ^ l4) & 3;
      const int g1 = (((l15 >> 3) | 2) ^ l4) & 3;
      Plds[w][row * 32 + (g0 << 3) + (l15 & 7)] = f2bf(p0);
      Plds[w][row * 32 + (g1 << 3) + (l15 & 7)] = f2bf(p1);
    }
    __syncthreads();  // RAW: VtS/Plds writes visible
#pragma unroll
    for (int ch = 0; ch < 8; ++ch) {
      o[ch][0] *= alpha[0]; o[ch][1] *= alpha[1];
      o[ch][2] *= alpha[2]; o[ch][3] *= alpha[3];
    }
    // PV: A=P from Plds (swizzled read), B=V^T from VtS (swizzled read)
    const bf16x8 pa = *(const bf16x8*)&Plds[w][l15 * 32 + ((l4 ^ (l15 >> 2)) << 3)];
#pragma unroll
    for (int ch = 0; ch < 8; ++ch) {
      const int dh = ch * 16 + l15;
      const int g = (l4 ^ ((2 * ch + (l15 >> 3)) & 3)) << 3;
      const bf16x8 vbf = *(const bf16x8*)&VtS[dh * 32 + g];
      o[ch] = __builtin_amdgcn_mfma_f32_16x16x32_bf16(pa, vbf, o[ch], 0, 0, 0);
    }
  }
  float invl[4];
#pragma unroll
  for (int r = 0; r < 4; ++r) invl[r] = 1.0f / lrow[r];
#pragma unroll
  for (int ch = 0; ch < 8; ++ch)
#pragma unroll
    for (int r = 0; r < 4; ++r) {
      const int gq = q0 + l4 * 4 + r;
      ctx[(size_t)(b * 2048 + gq) * 2048 + h * 128 + ch * 16 + l15] =
          f2bf(o[ch][r] * invl[r]);
    }
}

extern "C" void kernel_launch(void* const* d_in, const int* in_sizes, int n_in,
                              void* d_out, int out_size, void* d_ws, size_t ws_size,
                              hipStream_t stream) {
  const float* x     = (const float*)d_in[0];   // (2,2048,2048) fp32
  const float* wqkv  = (const float*)d_in[1];   // (6144,2048) fp32
  const float* wproj = (const float*)d_in[2];   // (2048,2048) fp32
  const int*   soff  = (const int*)d_in[3];     // scalar int
  float* out = (float*)d_out;                   // (2,2048,2048) fp32

  // ws layout (u16 units), total 100.7 MB:
  u16* wsu    = (u16*)d_ws;
  u16* xb     = wsu;                    //  8388608 u16 (dead after gemm1)
  u16* wqkvb  = xb + 8388608;           // 12582912 u16
  u16* wprojb = wqkvb + 12582912;       //  4194304 u16
  u16* qkv    = wprojb + 4194304;       // 25165824 u16
  u16* ctx    = xb;                     // reuse xb region

  f32_to_bf16<<<8192, 256, 0, stream>>>(x, xb, 2097152);
  f32_to_bf16<<<12288, 256, 0, stream>>>(wqkv, wqkvb, 3145728);
  f32_to_bf16<<<4096, 256, 0, stream>>>(wproj, wprojb, 1048576);

  gemm_bt<false><<<dim3(48, 32), 256, 0, stream>>>(xb, wqkvb, qkv, 4096, 6144, 2048);
  rope_kernel<<<16384, 256, 0, stream>>>(qkv, soff);
  attn_kernel<<<dim3(32, 32), 256, 0, stream>>>(qkv, ctx);
  gemm_bt<true><<<dim3(16, 32), 256, 0, stream>>>(ctx, wprojb, out, 4096, 2048, 2048);
}

// Round 10
// 316.398 us; speedup vs baseline: 10.6919x; 1.3524x over previous
//
#include <hip/hip_runtime.h>
#include <math.h>

typedef __bf16 bf16x8 __attribute__((ext_vector_type(8)));
typedef float f32x4 __attribute__((ext_vector_type(4)));
typedef unsigned short u16;
typedef unsigned short u16x4 __attribute__((ext_vector_type(4)));
typedef unsigned short u16x8 __attribute__((ext_vector_type(8)));
typedef unsigned int u32;

#define AS1 __attribute__((address_space(1)))
#define AS3 __attribute__((address_space(3)))

static __device__ __forceinline__ float bf2f(u16 u) {
  union { u32 i; float f; } v; v.i = ((u32)u) << 16; return v.f;
}
static __device__ __forceinline__ u16 f2bf(float f) {
  union { float f; u32 i; } v; v.f = f;
  u32 r = v.i + 0x7FFFu + ((v.i >> 16) & 1u);
  return (u16)(r >> 16);
}

// ---- one-shot fp32 -> bf16 convert (memory-bound, coalesced) ----
__global__ __launch_bounds__(256)
void f32_to_bf16(const float* __restrict__ src, u16* __restrict__ dst, int n4) {
  const int gid = blockIdx.x * 256 + threadIdx.x;
  if (gid >= n4) return;
  const float4 v = ((const float4*)src)[gid];
  u16x4 p = {f2bf(v.x), f2bf(v.y), f2bf(v.z), f2bf(v.w)};
  ((u16x4*)dst)[gid] = p;
}

// ---- GEMM: C[M,N] = A[M,K] @ B[N,K]^T, bf16 A/B via global_load_lds ----
// m97 structure: 128x128 tile, BK=32, 4 waves (2x2), 2 barriers/K-step.
template <bool CF32>
__global__ __launch_bounds__(256, 2)
void gemm_bt(const u16* __restrict__ A, const u16* __restrict__ B,
             void* __restrict__ Cp, int M, int N, int K) {
  __shared__ __align__(16) u16 As[128 * 32];
  __shared__ __align__(16) u16 Bs[128 * 32];
  const int tid = threadIdx.x;
  const int lane = tid & 63;
  const int wid = tid >> 6;
  const int wr = wid >> 1, wc = wid & 1;
  const int l15 = lane & 15, l4 = lane >> 4;
  const int m0 = blockIdx.y * 128, n0 = blockIdx.x * 128;

  const f32x4 fzero = {0.f, 0.f, 0.f, 0.f};
  f32x4 acc[4][4];
#pragma unroll
  for (int i = 0; i < 4; ++i)
#pragma unroll
    for (int j = 0; j < 4; ++j) acc[i][j] = fzero;

  for (int kt = 0; kt < K; kt += 32) {
#pragma unroll
    for (int i = 0; i < 2; ++i) {
      const int c = wid * 64 + i * 256 + lane;
      const u16* ga = A + (size_t)(m0 + (c >> 2)) * K + kt + (c & 3) * 8;
      const u16* gb = B + (size_t)(n0 + (c >> 2)) * K + kt + (c & 3) * 8;
      __builtin_amdgcn_global_load_lds((AS1 void*)ga,
          (AS3 void*)(As + (size_t)(wid * 64 + i * 256) * 8), 16, 0, 0);
      __builtin_amdgcn_global_load_lds((AS1 void*)gb,
          (AS3 void*)(Bs + (size_t)(wid * 64 + i * 256) * 8), 16, 0, 0);
    }
    __syncthreads();
    bf16x8 af[4], bfr[4];
#pragma unroll
    for (int m = 0; m < 4; ++m)
      af[m] = *(const bf16x8*)&As[(wr * 64 + m * 16 + l15) * 32 + l4 * 8];
#pragma unroll
    for (int n = 0; n < 4; ++n)
      bfr[n] = *(const bf16x8*)&Bs[(wc * 64 + n * 16 + l15) * 32 + l4 * 8];
#pragma unroll
    for (int m = 0; m < 4; ++m)
#pragma unroll
      for (int n = 0; n < 4; ++n)
        acc[m][n] = __builtin_amdgcn_mfma_f32_16x16x32_bf16(af[m], bfr[n], acc[m][n], 0, 0, 0);
    __syncthreads();
  }

#pragma unroll
  for (int m = 0; m < 4; ++m)
#pragma unroll
    for (int r = 0; r < 4; ++r) {
      const int gm = m0 + wr * 64 + m * 16 + l4 * 4 + r;
      if constexpr (CF32) {
        float* crow = (float*)Cp + (size_t)gm * N + n0 + wc * 64 + l15;
#pragma unroll
        for (int n = 0; n < 4; ++n) crow[n * 16] = acc[m][n][r];
      } else {
        u16* crow = (u16*)Cp + (size_t)gm * N + n0 + wc * 64 + l15;
#pragma unroll
        for (int n = 0; n < 4; ++n) crow[n * 16] = f2bf(acc[m][n][r]);
      }
    }
}

// ---- RoPE in-place on q,k slots of qkv [B=2][T=2048][3][H=16][Dh=128] ----
__global__ __launch_bounds__(256)
void rope_kernel(u16* __restrict__ qkv, const int* __restrict__ seq_off) {
  const int idx = blockIdx.x * 256 + threadIdx.x;  // 4194304 threads
  const int d = idx & 63;
  const int h = (idx >> 6) & 15;
  const int t = (idx >> 10) & 2047;
  const int b = idx >> 21;
  const float pos = (float)(seq_off[0] + t);
  const float inv = expf((float)d * (-0.14391156509731588f));  // -ln(1e4)/64
  float sv, cv;
  sincosf(pos * inv, &sv, &cv);
  const size_t base = ((size_t)(b * 2048 + t)) * 6144 + h * 128 + d;
  const float q1 = bf2f(qkv[base]);
  const float q2 = bf2f(qkv[base + 64]);
  qkv[base] = f2bf(q1 * cv - q2 * sv);
  qkv[base + 64] = f2bf(q2 * cv + q1 * sv);
  const float k1 = bf2f(qkv[base + 2048]);
  const float k2 = bf2f(qkv[base + 2048 + 64]);
  qkv[base + 2048] = f2bf(k1 * cv - k2 * sv);
  qkv[base + 2048 + 64] = f2bf(k2 * cv + k1 * sv);
}

// ---- Flash attention v3: causal, fixed-shift softmax, 1 barrier/tile ----
// 4 waves/block, 16 q-rows each; block does q-tile (31-p) then p (uniform 66
// tiles). K staged shared via global_load_lds with pre-swizzled source
// (chunk ^= row&15, LDS linear); V^T reg-staged with r9 swizzle; both
// double-buffered. Softmax: P = exp(s*scale - 12) (shift-invariant, no max
// tracking, no rescale, no cross-lane ops in loop).
__global__ __launch_bounds__(256, 2)
void attn_kernel(const u16* __restrict__ qkv, u16* __restrict__ ctx) {
  __shared__ __align__(16) u16 kbuf[2][32 * 128];   // K tile [kv][dh], swizzled chunks
  __shared__ __align__(16) u16 vbuf[2][128 * 32];   // V^T [dh][kvpair-u32], swizzled
  __shared__ __align__(16) u16 Plds[4][16 * 32];    // per-wave P, swizzled
  const int tid = threadIdx.x, lane = tid & 63, w = tid >> 6;
  const int l15 = lane & 15, l4 = lane >> 4;
  const int bh = blockIdx.y;
  const int b = bh >> 4, h = bh & 15;
  const u16* Qb = qkv + (size_t)b * 2048 * 6144 + h * 128;
  const u16* Kb = Qb + 2048;
  const u16* Vb = Qb + 4096;

  // V cooperative staging ids (256 threads cover 32kv x 128dh)
  const int sp = tid & 15;                 // kv pair 0..15
  const int sB = tid >> 4;                 // dh block 0..15 (8 dh each)
  const int sgp = sB & 1;
  const int swg = (((sp >> 2) ^ (sB & 3)) << 3) + ((sp & 3) << 1);
  // K gll slots (per wave: 2 calls x 64 lanes x 16B = 2KB; 4 waves = 8KB tile)
  const int ks0 = (w * 2 + 0) * 64 + lane;
  const int ks1 = (w * 2 + 1) * 64 + lane;
  const int kr0 = ks0 >> 4, kc0 = (ks0 & 15) ^ (kr0 & 15);
  const int kr1 = ks1 >> 4, kc1 = (ks1 & 15) ^ (kr1 & 15);

  const float scale = 0.08838834764831845f;  // 1/sqrt(128)
  const float M0 = 12.0f;                    // fixed softmax shift
  const f32x4 fzero = {0.f, 0.f, 0.f, 0.f};

  for (int pass = 0; pass < 2; ++pass) {
    const int qt = pass ? (int)blockIdx.x : (31 - (int)blockIdx.x);
    const int q0 = qt * 64 + w * 16;
    const int nt_blk = qt * 2 + 2;           // uniform across waves

    bf16x8 qf[4];
#pragma unroll
    for (int c = 0; c < 4; ++c)
      qf[c] = *(const bf16x8*)(Qb + (size_t)(q0 + l15) * 6144 + c * 32 + l4 * 8);

    f32x4 o[8];
#pragma unroll
    for (int ch = 0; ch < 8; ++ch) o[ch] = fzero;
    float lpart[4] = {0.f, 0.f, 0.f, 0.f};

    __syncthreads();  // prior pass's PV reads drained before restaging buf0
    // prologue: stage K(0), V(0) into buffer 0
    __builtin_amdgcn_global_load_lds((AS1 void*)(Kb + (size_t)kr0 * 6144 + kc0 * 8),
        (AS3 void*)(&kbuf[0][(w * 2 + 0) * 512]), 16, 0, 0);
    __builtin_amdgcn_global_load_lds((AS1 void*)(Kb + (size_t)kr1 * 6144 + kc1 * 8),
        (AS3 void*)(&kbuf[0][(w * 2 + 1) * 512]), 16, 0, 0);
    {
      const u16* vp = Vb + (size_t)(2 * sp) * 6144 + 8 * sB;
      const u16x8 v0 = *(const u16x8*)vp;
      const u16x8 v1 = *(const u16x8*)(vp + 6144);
#pragma unroll
      for (int e = 0; e < 8; ++e) {
        const int s = e ^ sgp;
        const int dh = 8 * sB + s;
        *(u32*)&vbuf[0][dh * 32 + swg] = (u32)v0[s] | ((u32)v1[s] << 16);
      }
    }
    __syncthreads();  // staged K(0)/V(0) visible

    for (int t = 0; t < nt_blk; ++t) {
      const int cur = t & 1, nxtb = cur ^ 1;
      const int kv0 = t * 32;
      const bool has_next = (t + 1 < nt_blk);
      u16x8 v0, v1;
      if (has_next) {  // issue V(t+1) register loads early (cover = QK+softmax)
        const u16* vp = Vb + (size_t)(kv0 + 32 + 2 * sp) * 6144 + 8 * sB;
        v0 = *(const u16x8*)vp;
        v1 = *(const u16x8*)(vp + 6144);
      }
      // QK from kbuf[cur] (swizzled, conflict-light ds_read_b128)
      f32x4 s0 = fzero, s1 = fzero;
#pragma unroll
      for (int c = 0; c < 4; ++c) {
        const bf16x8 kf = *(const bf16x8*)&kbuf[cur][l15 * 128 + (((c * 4 + l4) ^ l15) << 3)];
        s0 = __builtin_amdgcn_mfma_f32_16x16x32_bf16(qf[c], kf, s0, 0, 0, 0);
      }
#pragma unroll
      for (int c = 0; c < 4; ++c) {
        const bf16x8 kf = *(const bf16x8*)&kbuf[cur][(16 + l15) * 128 + (((c * 4 + l4) ^ l15) << 3)];
        s1 = __builtin_amdgcn_mfma_f32_16x16x32_bf16(qf[c], kf, s1, 0, 0, 0);
      }
      // fixed-shift softmax: no max tracking, no cross-lane ops
#pragma unroll
      for (int r = 0; r < 4; ++r) {
        const int qg = q0 + l4 * 4 + r;
        const float p0 = (kv0 + l15 <= qg) ? __expf(fmaf(s0[r], scale, -M0)) : 0.f;
        const float p1 = (kv0 + 16 + l15 <= qg) ? __expf(fmaf(s1[r], scale, -M0)) : 0.f;
        lpart[r] += p0 + p1;
        const int row = l4 * 4 + r;
        const int g0 = ((l15 >> 3) ^ l4) & 3;
        const int g1 = (((l15 >> 3) | 2) ^ l4) & 3;
        Plds[w][row * 32 + g0 * 8 + (l15 & 7)] = f2bf(p0);
        Plds[w][row * 32 + g1 * 8 + (l15 & 7)] = f2bf(p1);
      }
      __syncthreads();  // the ONE barrier: P visible, V(t)/K(t) settled, WAR safe
      if (has_next) {  // issue K(t+1) async stage (lands by next barrier's drain)
        __builtin_amdgcn_global_load_lds((AS1 void*)(Kb + (size_t)(kv0 + 32 + kr0) * 6144 + kc0 * 8),
            (AS3 void*)(&kbuf[nxtb][(w * 2 + 0) * 512]), 16, 0, 0);
        __builtin_amdgcn_global_load_lds((AS1 void*)(Kb + (size_t)(kv0 + 32 + kr1) * 6144 + kc1 * 8),
            (AS3 void*)(&kbuf[nxtb][(w * 2 + 1) * 512]), 16, 0, 0);
      }
      // PV from vbuf[cur]
      const bf16x8 pa = *(const bf16x8*)&Plds[w][l15 * 32 + ((l4 ^ (l15 >> 2)) << 3)];
#pragma unroll
      for (int ch = 0; ch < 8; ++ch) {
        const int dh = ch * 16 + l15;
        const int g = (l4 ^ ((2 * ch + (l15 >> 3)) & 3)) << 3;
        const bf16x8 vbf = *(const bf16x8*)&vbuf[cur][dh * 32 + g];
        o[ch] = __builtin_amdgcn_mfma_f32_16x16x32_bf16(pa, vbf, o[ch], 0, 0, 0);
      }
      // write staged V(t+1) (regs were force-drained at the barrier)
      if (has_next) {
#pragma unroll
        for (int e = 0; e < 8; ++e) {
          const int s = e ^ sgp;
          const int dh = 8 * sB + s;
          *(u32*)&vbuf[nxtb][dh * 32 + swg] = (u32)v0[s] | ((u32)v1[s] << 16);
        }
      }
    }
    // epilogue: one cross-lane reduce per pass, normalize, store
    float invl[4];
#pragma unroll
    for (int r = 0; r < 4; ++r) {
      float l = lpart[r];
      l += __shfl_xor(l, 1);
      l += __shfl_xor(l, 2);
      l += __shfl_xor(l, 4);
      l += __shfl_xor(l, 8);
      invl[r] = 1.0f / l;
    }
#pragma unroll
    for (int ch = 0; ch < 8; ++ch)
#pragma unroll
      for (int r = 0; r < 4; ++r) {
        const int gq = q0 + l4 * 4 + r;
        ctx[(size_t)(b * 2048 + gq) * 2048 + h * 128 + ch * 16 + l15] =
            f2bf(o[ch][r] * invl[r]);
      }
  }
}

extern "C" void kernel_launch(void* const* d_in, const int* in_sizes, int n_in,
                              void* d_out, int out_size, void* d_ws, size_t ws_size,
                              hipStream_t stream) {
  const float* x     = (const float*)d_in[0];   // (2,2048,2048) fp32
  const float* wqkv  = (const float*)d_in[1];   // (6144,2048) fp32
  const float* wproj = (const float*)d_in[2];   // (2048,2048) fp32
  const int*   soff  = (const int*)d_in[3];     // scalar int
  float* out = (float*)d_out;                   // (2,2048,2048) fp32

  // ws layout (u16 units), total 100.7 MB:
  u16* wsu    = (u16*)d_ws;
  u16* xb     = wsu;                    //  8388608 u16 (dead after gemm1)
  u16* wqkvb  = xb + 8388608;           // 12582912 u16
  u16* wprojb = wqkvb + 12582912;       //  4194304 u16
  u16* qkv    = wprojb + 4194304;       // 25165824 u16
  u16* ctx    = xb;                     // reuse xb region

  f32_to_bf16<<<8192, 256, 0, stream>>>(x, xb, 2097152);
  f32_to_bf16<<<12288, 256, 0, stream>>>(wqkv, wqkvb, 3145728);
  f32_to_bf16<<<4096, 256, 0, stream>>>(wproj, wprojb, 1048576);

  gemm_bt<false><<<dim3(48, 32), 256, 0, stream>>>(xb, wqkvb, qkv, 4096, 6144, 2048);
  rope_kernel<<<16384, 256, 0, stream>>>(qkv, soff);
  attn_kernel<<<dim3(16, 32), 256, 0, stream>>>(qkv, ctx);
  gemm_bt<true><<<dim3(16, 32), 256, 0, stream>>>(ctx, wprojb, out, 4096, 2048, 2048);
}